// Round 3
// baseline (123.002 us; speedup 1.0000x reference)
//
#include <hip/hip_runtime.h>

// SpatialTransformer bilinear sampling, B=16 H=512 W=512 C=16 fp32.
// Round 3: 4 vertical pixels per thread (2x MLP, shared source window),
// XCD-chunked work swizzle (per-XCD L2 locality), branchless clamp+mask
// gathers, NT stores for out / NT loads for def (preserve image in L3).

#define H_ 512
#define W_ 512

typedef float v2f __attribute__((ext_vector_type(2)));
typedef float v4f __attribute__((ext_vector_type(4)));

__device__ __forceinline__ v4f bilerp_quad(const float* __restrict__ base,
                                           int cq, int xw, int y, v2f d)
{
    // coords in padded frame (pad=1), exactly per reference
    float xf = d.x + (float)xw + 1.0f;
    float yf = d.y + (float)y  + 1.0f;

    int x0 = (int)floorf(xf);
    int y0 = (int)floorf(yf);
    int x1 = min(max(x0 + 1, 0), W_ + 1);
    int y1 = min(max(y0 + 1, 0), H_ + 1);
    x0 = min(max(x0, 0), W_ + 1);
    y0 = min(max(y0, 0), H_ + 1);

    float dx = (float)x1 - xf;
    float dy = (float)y1 - yf;

    // padded index i maps to real pixel i-1 iff 1 <= i <= 512, else zero pad
    float vx0 = (x0 >= 1 && x0 <= W_) ? 1.0f : 0.0f;
    float vx1 = (x1 >= 1 && x1 <= W_) ? 1.0f : 0.0f;
    float vy0 = (y0 >= 1 && y0 <= H_) ? 1.0f : 0.0f;
    float vy1 = (y1 >= 1 && y1 <= H_) ? 1.0f : 0.0f;

    int xc0 = min(max(x0, 1), W_) - 1;
    int xc1 = min(max(x1, 1), W_) - 1;
    int yc0 = min(max(y0, 1), H_) - 1;
    int yc1 = min(max(y1, 1), H_) - 1;

    const float* pa = base + ((size_t)((yc0 << 9) | xc0) << 4) + cq;
    const float* pb = base + ((size_t)((yc1 << 9) | xc0) << 4) + cq;
    const float* pc = base + ((size_t)((yc0 << 9) | xc1) << 4) + cq;
    const float* pd = base + ((size_t)((yc1 << 9) | xc1) << 4) + cq;

    v4f Ia = *reinterpret_cast<const v4f*>(pa);
    v4f Ib = *reinterpret_cast<const v4f*>(pb);
    v4f Ic = *reinterpret_cast<const v4f*>(pc);
    v4f Id = *reinterpret_cast<const v4f*>(pd);

    float wa = dx * dy                   * (vx0 * vy0);
    float wb = dx * (1.0f - dy)          * (vx0 * vy1);
    float wc = (1.0f - dx) * dy          * (vx1 * vy0);
    float wd = (1.0f - dx) * (1.0f - dy) * (vx1 * vy1);

    return wa * Ia + wb * Ib + wc * Ic + wd * Id;
}

__global__ __launch_bounds__(256) void st_bilinear4(
    const float* __restrict__ img,   // [B,H,W,C]
    const float* __restrict__ def,   // [B,H,W,2]
    float* __restrict__ out)         // [B,H,W,C]
{
    // XCD-chunked bijective swizzle: 16384 blocks, 8 XCDs, 2048-block chunks.
    // XCD k (hw round-robin on blockIdx) processes contiguous work chunk k.
    int sbid = (blockIdx.x & 7) * (16384 >> 3) + (blockIdx.x >> 3);
    int tid  = sbid * 256 + threadIdx.x;      // [0, 4194304)

    int cq   = (tid & 3) << 2;                // channel offset 0,4,8,12
    int unit = tid >> 2;                      // [0, 1048576): one column x 4 rows
    int xw   = unit & 511;
    int yg   = (unit >> 9) & 127;             // row-group (4 rows each)
    int b    = unit >> 16;
    int yr   = yg << 2;

    int p0 = (b << 18) | (yr << 9) | xw;      // pixel index of first row

    const float* base = img + ((size_t)b << 22);
    const float* dp   = def + ((size_t)p0 << 1);

    v2f d0 = __builtin_nontemporal_load(reinterpret_cast<const v2f*>(dp));
    v2f d1 = __builtin_nontemporal_load(reinterpret_cast<const v2f*>(dp + (W_ << 1)));
    v2f d2 = __builtin_nontemporal_load(reinterpret_cast<const v2f*>(dp + (W_ << 2)));
    v2f d3 = __builtin_nontemporal_load(reinterpret_cast<const v2f*>(dp + 3 * (W_ << 1)));

    v4f r0 = bilerp_quad(base, cq, xw, yr,     d0);
    v4f r1 = bilerp_quad(base, cq, xw, yr + 1, d1);
    v4f r2 = bilerp_quad(base, cq, xw, yr + 2, d2);
    v4f r3 = bilerp_quad(base, cq, xw, yr + 3, d3);

    float* op = out + ((size_t)p0 << 4) + cq;
    __builtin_nontemporal_store(r0, reinterpret_cast<v4f*>(op));
    __builtin_nontemporal_store(r1, reinterpret_cast<v4f*>(op + (W_ << 4)));
    __builtin_nontemporal_store(r2, reinterpret_cast<v4f*>(op + (W_ << 5)));
    __builtin_nontemporal_store(r3, reinterpret_cast<v4f*>(op + 3 * (W_ << 4)));
}

extern "C" void kernel_launch(void* const* d_in, const int* in_sizes, int n_in,
                              void* d_out, int out_size, void* d_ws, size_t ws_size,
                              hipStream_t stream) {
    const float* img = (const float*)d_in[0];   // moving_image [B,H,W,C]
    const float* def = (const float*)d_in[1];   // deformation  [B,H,W,2]
    float* out = (float*)d_out;

    const int total_threads = 16 * 512 * 512 * 4 / 4;  // 4 pixels per thread
    const int block = 256;
    const int grid = total_threads / block;            // 16384

    st_bilinear4<<<grid, block, 0, stream>>>(img, def, out);
}

// Round 4
// 100.262 us; speedup vs baseline: 1.2268x; 1.2268x over previous
//
#include <hip/hip_runtime.h>

// SpatialTransformer bilinear sampling, B=16 H=512 W=512 C=16 fp32.
// Round 4: back to 2 row-adjacent pixels/thread (R2 = 94.7us proven).
// Change vs R2: phase-split structure -- ALL address+weight math for both
// pixels first, then 8 clustered global_load_dwordx4 (max MLP), then FMAs.
// No XCD swizzle (R3 regression). NT def loads / NT out stores kept.

#define H_ 512
#define W_ 512

typedef float v2f __attribute__((ext_vector_type(2)));
typedef float v4f __attribute__((ext_vector_type(4)));

struct Quad {
    const float *pa, *pb, *pc, *pd;
    float wa, wb, wc, wd;
};

__device__ __forceinline__ Quad setup_quad(const float* __restrict__ base,
                                           int cq, int xw, int y, v2f d)
{
    // coords in padded frame (pad=1), exactly per reference
    float xf = d.x + (float)xw + 1.0f;
    float yf = d.y + (float)y  + 1.0f;

    int x0 = (int)floorf(xf);
    int y0 = (int)floorf(yf);
    int x1 = min(max(x0 + 1, 0), W_ + 1);
    int y1 = min(max(y0 + 1, 0), H_ + 1);
    x0 = min(max(x0, 0), W_ + 1);
    y0 = min(max(y0, 0), H_ + 1);

    float dx = (float)x1 - xf;
    float dy = (float)y1 - yf;

    // padded index i maps to real pixel i-1 iff 1 <= i <= 512, else zero pad
    float vx0 = (x0 >= 1 && x0 <= W_) ? 1.0f : 0.0f;
    float vx1 = (x1 >= 1 && x1 <= W_) ? 1.0f : 0.0f;
    float vy0 = (y0 >= 1 && y0 <= H_) ? 1.0f : 0.0f;
    float vy1 = (y1 >= 1 && y1 <= H_) ? 1.0f : 0.0f;

    int xc0 = min(max(x0, 1), W_) - 1;
    int xc1 = min(max(x1, 1), W_) - 1;
    int yc0 = min(max(y0, 1), H_) - 1;
    int yc1 = min(max(y1, 1), H_) - 1;

    Quad q;
    q.pa = base + ((size_t)((yc0 << 9) | xc0) << 4) + cq;
    q.pb = base + ((size_t)((yc1 << 9) | xc0) << 4) + cq;
    q.pc = base + ((size_t)((yc0 << 9) | xc1) << 4) + cq;
    q.pd = base + ((size_t)((yc1 << 9) | xc1) << 4) + cq;
    q.wa = dx * dy                   * (vx0 * vy0);
    q.wb = dx * (1.0f - dy)          * (vx0 * vy1);
    q.wc = (1.0f - dx) * dy          * (vx1 * vy0);
    q.wd = (1.0f - dx) * (1.0f - dy) * (vx1 * vy1);
    return q;
}

__global__ __launch_bounds__(256) void st_bilinear2b(
    const float* __restrict__ img,   // [B,H,W,C]
    const float* __restrict__ def,   // [B,H,W,2]
    float* __restrict__ out)         // [B,H,W,C]
{
    int tid = blockIdx.x * 256 + threadIdx.x;   // [0, 8388608)
    int cq  = (tid & 3) << 2;                   // channel offset 0,4,8,12
    int pp  = tid >> 2;                         // pixel-pair index
    int xw  = pp & 511;
    int yh  = (pp >> 9) & 255;
    int b   = pp >> 17;
    int yr  = yh << 1;                          // even row
    int p0  = (b << 18) | (yr << 9) | xw;       // pixel index of row yr
    int p1  = p0 + W_;                          // pixel index of row yr+1

    const float* base = img + ((size_t)b << 22);

    v2f d0 = __builtin_nontemporal_load(
        reinterpret_cast<const v2f*>(def + ((size_t)p0 << 1)));
    v2f d1 = __builtin_nontemporal_load(
        reinterpret_cast<const v2f*>(def + ((size_t)p1 << 1)));

    // Phase A: all address + weight arithmetic for both pixels.
    Quad q0 = setup_quad(base, cq, xw, yr,     d0);
    Quad q1 = setup_quad(base, cq, xw, yr + 1, d1);

    // Phase B: 8 clustered gathers (max memory-level parallelism).
    v4f Ia0 = *reinterpret_cast<const v4f*>(q0.pa);
    v4f Ib0 = *reinterpret_cast<const v4f*>(q0.pb);
    v4f Ic0 = *reinterpret_cast<const v4f*>(q0.pc);
    v4f Id0 = *reinterpret_cast<const v4f*>(q0.pd);
    v4f Ia1 = *reinterpret_cast<const v4f*>(q1.pa);
    v4f Ib1 = *reinterpret_cast<const v4f*>(q1.pb);
    v4f Ic1 = *reinterpret_cast<const v4f*>(q1.pc);
    v4f Id1 = *reinterpret_cast<const v4f*>(q1.pd);

    // Phase C: weighted sums + stores.
    v4f r0 = q0.wa * Ia0 + q0.wb * Ib0 + q0.wc * Ic0 + q0.wd * Id0;
    v4f r1 = q1.wa * Ia1 + q1.wb * Ib1 + q1.wc * Ic1 + q1.wd * Id1;

    float* op = out + ((size_t)p0 << 4) + cq;
    __builtin_nontemporal_store(r0, reinterpret_cast<v4f*>(op));
    __builtin_nontemporal_store(r1, reinterpret_cast<v4f*>(op + (W_ << 4)));
}

extern "C" void kernel_launch(void* const* d_in, const int* in_sizes, int n_in,
                              void* d_out, int out_size, void* d_ws, size_t ws_size,
                              hipStream_t stream) {
    const float* img = (const float*)d_in[0];   // moving_image [B,H,W,C]
    const float* def = (const float*)d_in[1];   // deformation  [B,H,W,2]
    float* out = (float*)d_out;

    const int total_threads = 16 * 512 * 512 * 4 / 2;  // 2 pixels per thread
    const int block = 256;
    const int grid = total_threads / block;            // 32768

    st_bilinear2b<<<grid, block, 0, stream>>>(img, def, out);
}